// Round 6
// baseline (775.047 us; speedup 1.0000x reference)
//
#include <hip/hip_runtime.h>

#define HH 512
#define WW 512
#define NB 4
#define NC 25              // final channel count: 1 + 12*2
#define HWs (HH * WW)

__device__ __forceinline__ int refl(int p, int n) {
    p = (p < 0) ? -p : p;
    p = (p >= n) ? (2 * n - 2 - p) : p;
    return p;
}

__global__ __launch_bounds__(256) void copy_x_kernel(const float* __restrict__ x,
                                                     float* __restrict__ out) {
    int t = blockIdx.x * 256 + threadIdx.x;   // NB*HWs/4 = 262144 threads
    int b = t >> 16;                          // HWs/4 = 65536 float4 per batch
    int r = t & 65535;
    const float4* src = (const float4*)(x + (size_t)b * HWs);
    float4* dst = (float4*)(out + (size_t)b * NC * HWs);
    dst[r] = src[r];
}

// Load taps [w0+E .. w0+E+3] of a row via aligned float4(s) + compile-time
// element selection (E mod 4 is a template constant -> free "shuffle").
// Edge lanes (window crosses image border) take a scalar reflect fallback.
template <int E>
__device__ __forceinline__ float4 tap4(const float* __restrict__ row, int w0) {
    constexpr int R = ((E % 4) + 4) % 4;      // sub-f4 shift
    constexpr int Q = (E - R) / 4;            // aligned f4 index offset
    if (E == 0) return *(const float4*)(row + w0);
    if (w0 + E >= 0 && w0 + E + 3 <= WW - 1) {
        float4 A = *(const float4*)(row + w0 + 4 * Q);
        if (R == 0) return A;
        float4 B = *(const float4*)(row + w0 + 4 * Q + 4);
        float a[8] = {A.x, A.y, A.z, A.w, B.x, B.y, B.z, B.w};
        float4 r;
        r.x = a[R]; r.y = a[R + 1]; r.z = a[R + 2]; r.w = a[R + 3];
        return r;
    }
    float4 r;
    r.x = row[refl(w0 + E + 0, WW)];
    r.y = row[refl(w0 + E + 1, WW)];
    r.z = row[refl(w0 + E + 2, WW)];
    r.w = row[refl(w0 + E + 3, WW)];
    return r;
}

// Thread = 4 consecutive cols x 1 row, 2 out channels. No LDS, no barriers.
// Per channel: 3 kh-rows x 3 kw float4 tap-groups (9-15 coalesced 1KB
// wave-loads) + 72 FMA. 1024 blocks -> 16 waves/CU.
template <int NIN, int DIL>
__global__ __launch_bounds__(256) void msd_layer(const float* __restrict__ wts,
                                                 const float* __restrict__ bias,
                                                 float* __restrict__ buf,
                                                 int layer) {
    int idx = blockIdx.x * 256 + threadIdx.x;   // 262144 threads
    int w0 = (idx & 127) << 2;                  // 4-col group
    int h = __builtin_amdgcn_readfirstlane((idx >> 7) & 511);
    int b = __builtin_amdgcn_readfirstlane(idx >> 16);

    int grow[3];
#pragma unroll
    for (int r = 0; r < 3; ++r) grow[r] = refl(h + (r - 1) * DIL, HH) * WW;

    const float b0 = bias[2 * layer];
    const float b1 = bias[2 * layer + 1];
    float a0[4] = {b0, b0, b0, b0};
    float a1[4] = {b1, b1, b1, b1};

    const float* base = buf + (size_t)b * NC * HWs;

    for (int c = 0; c < NIN; ++c) {
        const float* plane = base + (size_t)c * HWs;
        float wk0[9], wk1[9];
#pragma unroll
        for (int k = 0; k < 9; ++k) {
            wk0[k] = wts[c * 9 + k];             // out-ch 0 (uniform -> s_load)
            wk1[k] = wts[(NIN + c) * 9 + k];     // out-ch 1
        }
#pragma unroll
        for (int g = 0; g < 3; ++g) {
            const float* row = plane + grow[g];
            float4 tl = tap4<-DIL>(row, w0);
            float4 tc = tap4<0>(row, w0);
            float4 tr = tap4<DIL>(row, w0);
            const float* L = &tl.x;
            const float* C = &tc.x;
            const float* Rt = &tr.x;
#pragma unroll
            for (int j = 0; j < 4; ++j) {
                a0[j] = fmaf(L[j], wk0[g * 3 + 0], a0[j]);
                a0[j] = fmaf(C[j], wk0[g * 3 + 1], a0[j]);
                a0[j] = fmaf(Rt[j], wk0[g * 3 + 2], a0[j]);
                a1[j] = fmaf(L[j], wk1[g * 3 + 0], a1[j]);
                a1[j] = fmaf(C[j], wk1[g * 3 + 1], a1[j]);
                a1[j] = fmaf(Rt[j], wk1[g * 3 + 2], a1[j]);
            }
        }
    }

    size_t opix = (size_t)h * WW + (size_t)w0;
    float* o0 = buf + (size_t)(b * NC + NIN) * HWs + opix;
    float* o1 = o0 + HWs;
    float4 v0, v1;
    v0.x = fmaxf(a0[0], 0.f); v0.y = fmaxf(a0[1], 0.f);
    v0.z = fmaxf(a0[2], 0.f); v0.w = fmaxf(a0[3], 0.f);
    v1.x = fmaxf(a1[0], 0.f); v1.y = fmaxf(a1[1], 0.f);
    v1.z = fmaxf(a1[2], 0.f); v1.w = fmaxf(a1[3], 0.f);
    *(float4*)o0 = v0;
    *(float4*)o1 = v1;
}

extern "C" void kernel_launch(void* const* d_in, const int* in_sizes, int n_in,
                              void* d_out, int out_size, void* d_ws, size_t ws_size,
                              hipStream_t stream) {
    const float* x = (const float*)d_in[0];
    const float* bias = (const float*)d_in[1];
    float* out = (float*)d_out;

    const int blocks = (NB * HWs / 4) / 256;  // 1024

    copy_x_kernel<<<blocks, 256, 0, stream>>>(x, out);

#define LAYER(i, nin, dil) \
    msd_layer<nin, dil><<<blocks, 256, 0, stream>>>((const float*)d_in[2 + i], bias, out, i)

    LAYER(0, 1, 1);
    LAYER(1, 3, 2);
    LAYER(2, 5, 3);
    LAYER(3, 7, 4);
    LAYER(4, 9, 5);
    LAYER(5, 11, 6);
    LAYER(6, 13, 7);
    LAYER(7, 15, 8);
    LAYER(8, 17, 9);
    LAYER(9, 19, 10);
    LAYER(10, 21, 11);
    LAYER(11, 23, 12);
#undef LAYER
}

// Round 7
// 388.168 us; speedup vs baseline: 1.9967x; 1.9967x over previous
//
#include <hip/hip_runtime.h>

#define HH 512
#define WW 512
#define NB 4
#define NC 25              // final channel count: 1 + 12*2
#define HWs (HH * WW)

__device__ __forceinline__ int refl(int p, int n) {
    p = (p < 0) ? -p : p;
    p = (p >= n) ? (2 * n - 2 - p) : p;
    return p;
}

__global__ __launch_bounds__(256) void copy_x_kernel(const float* __restrict__ x,
                                                     float* __restrict__ out) {
    int t = blockIdx.x * 256 + threadIdx.x;   // NB*HWs/4 = 262144 threads
    int b = t >> 16;                          // HWs/4 = 65536 float4 per batch
    int r = t & 65535;
    const float4* src = (const float4*)(x + (size_t)b * HWs);
    float4* dst = (float4*)(out + (size_t)b * NC * HWs);
    dst[r] = src[r];
}

// Dilation-symmetry register reuse: thread owns 3 output rows spaced DIL
// apart (one column). The 5 loaded rows {h-d..h+3d} x 3 col-taps serve all
// 27 row-taps: 15 dword loads per 3 px (5 vals/px vs 9). Lane = consecutive
// col -> every load is a dense 256B wave-load (4 L1 lines); row bases scalar.
// Rows [3d*floor(512/3d), 512) (<=26) handled by a tail path in-kernel.
template <int NIN, int DIL>
__global__ __launch_bounds__(256) void msd_layer(const float* __restrict__ wts,
                                                 const float* __restrict__ bias,
                                                 float* __restrict__ buf,
                                                 int layer) {
    constexpr int M3 = 512 / (3 * DIL);
    constexpr int DM = DIL * M3;          // row-bases per image
    constexpr int SPAN = 3 * DM;          // rows covered by main path
    constexpr int RT = 512 - SPAN;        // tail rows (0..26)
    constexpr int TCH = (RT + 3) / 4;     // tail chunks of 4 rows
    constexpr int IMT = 512 * DM;         // main threads per image
    constexpr int NMAIN = 4 * IMT;

    const int t = blockIdx.x * 256 + threadIdx.x;
    const float b0 = bias[2 * layer];
    const float b1 = bias[2 * layer + 1];

    if (t < NMAIN) {
        const int img = t / IMT;                       // uniform per block
        const int u = t - img * IMT;
        const int bi = __builtin_amdgcn_readfirstlane(u >> 9);   // base index
        const int w = u & 511;                         // per-lane column
        const int k = bi / DIL, j = bi - k * DIL;
        const int h = 3 * DIL * k + j;                 // base output row (scalar)

        int rowoff[5];                                 // rows h+(r-1)*d, scalar
#pragma unroll
        for (int r = 0; r < 5; ++r) rowoff[r] = refl(h + (r - 1) * DIL, HH) * WW;
        int cw[3];                                     // per-lane col taps
#pragma unroll
        for (int q = 0; q < 3; ++q) cw[q] = refl(w + (q - 1) * DIL, WW);

        float a0[3] = {b0, b0, b0};
        float a1[3] = {b1, b1, b1};
        const float* base = buf + (size_t)img * NC * HWs;

        for (int c = 0; c < NIN; ++c) {
            const float* plane = base + (size_t)c * HWs;
            float v[5][3];
#pragma unroll
            for (int r = 0; r < 5; ++r) {
                const float* rowp = plane + rowoff[r];
#pragma unroll
                for (int q = 0; q < 3; ++q) v[r][q] = rowp[cw[q]];
            }
            float wk0[9], wk1[9];
#pragma unroll
            for (int kk = 0; kk < 9; ++kk) {
                wk0[kk] = wts[c * 9 + kk];             // uniform -> s_load
                wk1[kk] = wts[(NIN + c) * 9 + kk];
            }
#pragma unroll
            for (int al = 0; al < 3; ++al)
#pragma unroll
                for (int kr = 0; kr < 3; ++kr)
#pragma unroll
                    for (int kw = 0; kw < 3; ++kw) {
                        float vv = v[al + kr][kw];
                        a0[al] = fmaf(vv, wk0[kr * 3 + kw], a0[al]);
                        a1[al] = fmaf(vv, wk1[kr * 3 + kw], a1[al]);
                    }
        }

        float* o0 = buf + (size_t)(img * NC + NIN) * HWs;
        float* o1 = o0 + HWs;
#pragma unroll
        for (int al = 0; al < 3; ++al) {
            size_t off = (size_t)(h + al * DIL) * WW + (size_t)w;
            o0[off] = fmaxf(a0[al], 0.f);
            o1[off] = fmaxf(a1[al], 0.f);
        }
    } else if (RT > 0) {
        const int t2 = t - NMAIN;
        constexpr int PIT = 512 * TCH;
        const int img = t2 / PIT;
        const int u = t2 - img * PIT;
        const int s = __builtin_amdgcn_readfirstlane(u >> 9);
        const int w = u & 511;
        const int r0 = SPAN + 4 * s;

        int cw[3];
#pragma unroll
        for (int q = 0; q < 3; ++q) cw[q] = refl(w + (q - 1) * DIL, WW);
        int ro[3][4];
#pragma unroll
        for (int kr = 0; kr < 3; ++kr)
#pragma unroll
            for (int i = 0; i < 4; ++i)
                ro[kr][i] = refl(r0 + i + (kr - 1) * DIL, HH) * WW;

        float a0[4] = {b0, b0, b0, b0};
        float a1[4] = {b1, b1, b1, b1};
        const float* base = buf + (size_t)img * NC * HWs;

        for (int c = 0; c < NIN; ++c) {
            const float* plane = base + (size_t)c * HWs;
            float wk0[9], wk1[9];
#pragma unroll
            for (int kk = 0; kk < 9; ++kk) {
                wk0[kk] = wts[c * 9 + kk];
                wk1[kk] = wts[(NIN + c) * 9 + kk];
            }
#pragma unroll
            for (int i = 0; i < 4; ++i) {
                if (r0 + i < HH) {
#pragma unroll
                    for (int kr = 0; kr < 3; ++kr) {
                        const float* rowp = plane + ro[kr][i];
#pragma unroll
                        for (int kw = 0; kw < 3; ++kw) {
                            float vv = rowp[cw[kw]];
                            a0[i] = fmaf(vv, wk0[kr * 3 + kw], a0[i]);
                            a1[i] = fmaf(vv, wk1[kr * 3 + kw], a1[i]);
                        }
                    }
                }
            }
        }

        float* o0 = buf + (size_t)(img * NC + NIN) * HWs;
        float* o1 = o0 + HWs;
#pragma unroll
        for (int i = 0; i < 4; ++i) {
            if (r0 + i < HH) {
                size_t off = (size_t)(r0 + i) * WW + (size_t)w;
                o0[off] = fmaxf(a0[i], 0.f);
                o1[off] = fmaxf(a1[i], 0.f);
            }
        }
    }
}

extern "C" void kernel_launch(void* const* d_in, const int* in_sizes, int n_in,
                              void* d_out, int out_size, void* d_ws, size_t ws_size,
                              hipStream_t stream) {
    const float* x = (const float*)d_in[0];
    const float* bias = (const float*)d_in[1];
    float* out = (float*)d_out;

    copy_x_kernel<<<1024, 256, 0, stream>>>(x, out);

// blocks = (main threads + tail threads) / 256 = 8*DM + 8*TCH
#define GBLK(dil) (8 * ((512 / (3 * (dil))) * (dil)) \
                 + 8 * (((512 - 3 * ((512 / (3 * (dil))) * (dil))) + 3) / 4))
#define LAYER(i, nin, dil) \
    msd_layer<nin, dil><<<GBLK(dil), 256, 0, stream>>>((const float*)d_in[2 + i], bias, out, i)

    LAYER(0, 1, 1);
    LAYER(1, 3, 2);
    LAYER(2, 5, 3);
    LAYER(3, 7, 4);
    LAYER(4, 9, 5);
    LAYER(5, 11, 6);
    LAYER(6, 13, 7);
    LAYER(7, 15, 8);
    LAYER(8, 17, 9);
    LAYER(9, 19, 10);
    LAYER(10, 21, 11);
    LAYER(11, 23, 12);
#undef LAYER
#undef GBLK
}